// Round 1
// baseline (11471.491 us; speedup 1.0000x reference)
//
#include <hip/hip_runtime.h>

// Problem constants
#define B_    32
#define T_    2048
#define F_    64
#define H_    256
#define OUT_  64
#define G3_   768           // 3*H
#define NWG   32            // workgroups in the persistent GRU kernel
#define NITER (T_ + 1)      // pipelined: iter i computes h1[i] and h2[i-1]

// ws layout (bytes)
#define XN_BYTES   (B_ * T_ * F_ * 2)            // 8,388,608  fp16 LN(x)
#define PACK_OFF   XN_BYTES
#define PACK_ELEMS (B_ * H_)                     // 8192 fp16 per buffer
#define PACK_BYTES (4 * PACK_ELEMS * 2)          // h1[2 parity] + h2[2 parity]
#define CNT_OFF    (PACK_OFF + PACK_BYTES)

typedef _Float16 half8 __attribute__((ext_vector_type(8)));
typedef float    f32x4 __attribute__((ext_vector_type(4)));

__device__ __forceinline__ float sigf(float x) {
    x = fminf(fmaxf(x, -30.f), 30.f);
    return 1.f / (1.f + __expf(-x));
}
__device__ __forceinline__ float tanhfast(float x) {
    x = fminf(fmaxf(x, -15.f), 15.f);
    float e = __expf(2.f * x);
    return (e - 1.f) / (e + 1.f);
}

// ---------------------------------------------------------------------------
// Init: zero barrier counters + h-pack buffers, out = bias broadcast
// ---------------------------------------------------------------------------
__global__ void init_kernel(float* __restrict__ out, const float* __restrict__ bd,
                            _Float16* __restrict__ packs, unsigned int* __restrict__ cnt) {
    int t = blockIdx.x * 256 + threadIdx.x;              // 16*256 = 4096 threads
    if (t < B_ * OUT_) out[t] = bd[t & (OUT_ - 1)];
    if (t < NITER)     cnt[t] = 0u;
    for (int p = t; p < 4 * PACK_ELEMS; p += 4096) packs[p] = (_Float16)0.f;
}

// ---------------------------------------------------------------------------
// LayerNorm over F=64, output fp16. One 64-thread wave per (b,t) row.
// ---------------------------------------------------------------------------
__global__ __launch_bounds__(64) void ln_kernel(const float* __restrict__ x,
                                                const float* __restrict__ gamma,
                                                const float* __restrict__ beta,
                                                _Float16* __restrict__ xn) {
    const size_t row = blockIdx.x;
    const int k = threadIdx.x;
    float v = x[row * F_ + k];
    float s = v;
#pragma unroll
    for (int m = 32; m >= 1; m >>= 1) s += __shfl_xor(s, m, 64);
    const float mu = s * (1.f / 64.f);
    const float d = v - mu;
    float q = d * d;
#pragma unroll
    for (int m = 32; m >= 1; m >>= 1) q += __shfl_xor(q, m, 64);
    const float rs = rsqrtf(q * (1.f / 64.f) + 1e-3f);
    xn[row * F_ + k] = (_Float16)(d * rs * gamma[k] + beta[k]);
}

// ---------------------------------------------------------------------------
// Persistent fused 2-layer GRU scan + final dense.
// Grid = 32 WGs x 256 threads (cooperative). WG w owns h-indices [8w, 8w+8)
// of BOTH layers. Per iteration i: h1[i] = GRU1(h1[i-1], xn[i]),
// h2[i-1] = GRU2(h2[i-2], h1[i-1]). One device barrier per iteration.
// Weight B-fragments live in VGPRs for the whole kernel.
// ---------------------------------------------------------------------------
__global__ __launch_bounds__(256) void gru_main(
    const _Float16* __restrict__ xn,
    const float* __restrict__ k1, const float* __restrict__ rk1,
    const float* __restrict__ b1, const float* __restrict__ k2,
    const float* __restrict__ rk2, const float* __restrict__ b2,
    const float* __restrict__ wd, float* __restrict__ out,
    _Float16* __restrict__ packs, unsigned int* __restrict__ cnt) {
    const int w    = blockIdx.x;         // 0..31
    const int tid  = threadIdx.x;
    const int lane = tid & 63;
    const int wave = tid >> 6;           // 4 waves: (mt, nt)
    const int mt   = wave & 1;
    const int nt   = wave >> 1;
    const int ln   = lane & 15;
    const int quad = lane >> 4;

    // ---- B-operand fragments (MFMA 16x16x32 f16): lane holds B[k=quad*8+j][n=lane&15]
    // local col lc in [0,24): gate = lc>>3 (z,r,h), hidx = lc&7 -> global col gate*256 + 8w + hidx
    const int  lc    = nt * 16 + ln;
    const bool valid = (lc < 24);
    const int  gate  = lc >> 3;
    const int  hidx  = lc & 7;
    const int  gcol  = valid ? (gate * H_ + w * 8 + hidx) : 0;   // clamped: loads always in-bounds

    half8 fk1[2], frk1[8], fk2[8], frk2[8];
#pragma unroll
    for (int ks = 0; ks < 2; ++ks) {
        half8 f;
#pragma unroll
        for (int j = 0; j < 8; ++j) {
            const int k = ks * 32 + quad * 8 + j;
            const float v = k1[k * G3_ + gcol];
            f[j] = valid ? (_Float16)v : (_Float16)0.f;
        }
        fk1[ks] = f;
    }
#pragma unroll
    for (int ks = 0; ks < 8; ++ks) {
        half8 f1, f2, f3;
#pragma unroll
        for (int j = 0; j < 8; ++j) {
            const int k = ks * 32 + quad * 8 + j;
            const float v1 = rk1[k * G3_ + gcol];
            const float v2 = k2 [k * G3_ + gcol];
            const float v3 = rk2[k * G3_ + gcol];
            f1[j] = valid ? (_Float16)v1 : (_Float16)0.f;
            f2[j] = valid ? (_Float16)v2 : (_Float16)0.f;
            f3[j] = valid ? (_Float16)v3 : (_Float16)0.f;
        }
        frk1[ks] = f1; fk2[ks] = f2; frk2[ks] = f3;
    }

    // ---- gate-phase thread mapping: (batch bb, local idx jl); owns h[bb][8w+jl] of both layers
    const int jl = tid & 7;
    const int bb = tid >> 3;
    const int gc = w * 8 + jl;
    const float b1xz = b1[gc],        b1xr = b1[H_ + gc],        b1xh = b1[2 * H_ + gc];
    const float b1hz = b1[G3_ + gc],  b1hr = b1[G3_ + H_ + gc],  b1hh = b1[G3_ + 2 * H_ + gc];
    const float b2xz = b2[gc],        b2xr = b2[H_ + gc],        b2xh = b2[2 * H_ + gc];
    const float b2hz = b2[G3_ + gc],  b2hr = b2[G3_ + H_ + gc],  b2hh = b2[G3_ + 2 * H_ + gc];

    float h1m = 0.f, h2m = 0.f;   // fp32 masters, register-resident

    __shared__ float Cs[4][32][25];   // [xproj, inner1, x2, inner2][batch][local col], +1 pad
    __shared__ float hs[256];

    const int m = mt * 16 + ln;       // batch row for A fragments

    for (int i = 0; i < NITER; ++i) {
        const int rb = (i + 1) & 1;   // read parity  (gen i-1)
        const int wb = i & 1;         // write parity (gen i)
        const _Float16* h1r = packs + rb * PACK_ELEMS;
        const _Float16* h2r = packs + 2 * PACK_ELEMS + rb * PACK_ELEMS;
        _Float16* h1w = packs + wb * PACK_ELEMS;
        _Float16* h2w = packs + 2 * PACK_ELEMS + wb * PACK_ELEMS;

        f32x4 c0 = {0.f, 0.f, 0.f, 0.f};
        f32x4 c1 = c0, c2 = c0, c3 = c0;

        if (i < T_) {   // xproj for layer-1 step i (K=64)
#pragma unroll
            for (int ks = 0; ks < 2; ++ks) {
                half8 a = *reinterpret_cast<const half8*>(
                    xn + ((size_t)m * T_ + i) * F_ + ks * 32 + quad * 8);
                c0 = __builtin_amdgcn_mfma_f32_16x16x32_f16(a, fk1[ks], c0, 0, 0, 0);
            }
        }
#pragma unroll
        for (int ks = 0; ks < 8; ++ks) {   // h1[i-1] feeds rk1 (inner1) and k2 (x2)
            half8 a1 = *reinterpret_cast<const half8*>(h1r + m * H_ + ks * 32 + quad * 8);
            c1 = __builtin_amdgcn_mfma_f32_16x16x32_f16(a1, frk1[ks], c1, 0, 0, 0);
            c2 = __builtin_amdgcn_mfma_f32_16x16x32_f16(a1, fk2[ks],  c2, 0, 0, 0);
        }
#pragma unroll
        for (int ks = 0; ks < 8; ++ks) {   // h2[i-2] feeds rk2 (inner2)
            half8 a2 = *reinterpret_cast<const half8*>(h2r + m * H_ + ks * 32 + quad * 8);
            c3 = __builtin_amdgcn_mfma_f32_16x16x32_f16(a2, frk2[ks], c3, 0, 0, 0);
        }

        // C/D layout: col = lane&15, row = quad*4 + reg
        if (valid) {
            const int r0 = mt * 16 + quad * 4;
#pragma unroll
            for (int rr = 0; rr < 4; ++rr) {
                Cs[0][r0 + rr][lc] = c0[rr];
                Cs[1][r0 + rr][lc] = c1[rr];
                Cs[2][r0 + rr][lc] = c2[rr];
                Cs[3][r0 + rr][lc] = c3[rr];
            }
        }
        __syncthreads();

        if (i < T_) {   // layer-1 gate combine for step i
            const float xz = Cs[0][bb][jl]      + b1xz;
            const float xr = Cs[0][bb][8 + jl]  + b1xr;
            const float xh = Cs[0][bb][16 + jl] + b1xh;
            const float rz = Cs[1][bb][jl]      + b1hz;
            const float rr = Cs[1][bb][8 + jl]  + b1hr;
            const float rh = Cs[1][bb][16 + jl] + b1hh;
            const float z  = sigf(xz + rz);
            const float r  = sigf(xr + rr);
            const float hh = tanhfast(xh + r * rh);
            h1m = z * h1m + (1.f - z) * hh;
            h1w[bb * H_ + gc] = (_Float16)h1m;
        }
        if (i >= 1) {   // layer-2 gate combine for step i-1
            const float xz = Cs[2][bb][jl]      + b2xz;
            const float xr = Cs[2][bb][8 + jl]  + b2xr;
            const float xh = Cs[2][bb][16 + jl] + b2xh;
            const float rz = Cs[3][bb][jl]      + b2hz;
            const float rr = Cs[3][bb][8 + jl]  + b2hr;
            const float rh = Cs[3][bb][16 + jl] + b2hh;
            const float z  = sigf(xz + rz);
            const float r  = sigf(xr + rr);
            const float hh = tanhfast(xh + r * rh);
            h2m = z * h2m + (1.f - z) * hh;
            h2w[bb * H_ + gc] = (_Float16)h2m;
        }
        __syncthreads();   // all pack stores complete (syncthreads drains vmcnt)

        if (i < T_) {      // device barrier: publish gen-i packs to all WGs
            if (tid == 0) {
                __threadfence();   // wb L2 -> coherence point (cross-XCD visibility)
                __hip_atomic_fetch_add(&cnt[i], 1u, __ATOMIC_RELAXED, __HIP_MEMORY_SCOPE_AGENT);
                while (__hip_atomic_load(&cnt[i], __ATOMIC_RELAXED, __HIP_MEMORY_SCOPE_AGENT) < NWG) {
                    __builtin_amdgcn_s_sleep(8);
                }
                __threadfence();   // inv L1/L2 before next iteration's pack reads
            }
            __syncthreads();
        }
    }

    // ---- final dense: out[b][o] += sum_j h2[b][8w+j] * wd[8w+j][o]  (out pre-init to bd)
    hs[tid] = h2m;
    __syncthreads();
    const int o  = tid & 63;
    const int bq = tid >> 6;
    for (int pass = 0; pass < 8; ++pass) {
        const int b = pass * 4 + bq;
        float acc = 0.f;
#pragma unroll
        for (int j = 0; j < 8; ++j) acc += hs[b * 8 + j] * wd[(w * 8 + j) * OUT_ + o];
        atomicAdd(&out[b * OUT_ + o], acc);
    }
}

// ---------------------------------------------------------------------------
extern "C" void kernel_launch(void* const* d_in, const int* in_sizes, int n_in,
                              void* d_out, int out_size, void* d_ws, size_t ws_size,
                              hipStream_t stream) {
    const float* x     = (const float*)d_in[0];
    const float* gamma = (const float*)d_in[1];
    const float* beta  = (const float*)d_in[2];
    const float* k1    = (const float*)d_in[3];
    const float* rk1   = (const float*)d_in[4];
    const float* b1    = (const float*)d_in[5];
    const float* k2    = (const float*)d_in[6];
    const float* rk2   = (const float*)d_in[7];
    const float* b2    = (const float*)d_in[8];
    const float* wd    = (const float*)d_in[9];
    const float* bd    = (const float*)d_in[10];
    float* out = (float*)d_out;

    char* ws = (char*)d_ws;
    _Float16*     xn    = (_Float16*)ws;
    _Float16*     packs = (_Float16*)(ws + PACK_OFF);
    unsigned int* cnt   = (unsigned int*)(ws + CNT_OFF);

    hipLaunchKernelGGL(init_kernel, dim3(16), dim3(256), 0, stream, out, bd, packs, cnt);
    hipLaunchKernelGGL(ln_kernel, dim3(B_ * T_), dim3(64), 0, stream, x, gamma, beta, xn);

    void* args[] = {(void*)&xn, (void*)&k1, (void*)&rk1, (void*)&b1, (void*)&k2,
                    (void*)&rk2, (void*)&b2, (void*)&wd, (void*)&out, (void*)&packs, (void*)&cnt};
    hipLaunchCooperativeKernel((void*)gru_main, dim3(NWG), dim3(256), args, 0, stream);
}